// Round 5
// baseline (3374.710 us; speedup 1.0000x reference)
//
#include <hip/hip_runtime.h>
#include <math.h>

#define NEGV   (-1e9f)
#define NB     8
#define CIN    512
#define CM     512
#define HH     64
#define WW     64
#define NA     9
#define KA     (HH*WW*NA)     /* 36864 */
#define NPRE   3000
#define NPOST  300

/* d_out float offsets (outputs concatenated in return order) */
#define OFF_SC  1179648       /* 8*36864*4 */
#define OFF_ROI 1769472       /* + 8*36864*2 */
#define OFF_IDX 1779072       /* + 8*300*4 */
#define OFF_ANC 1781472       /* + 8*300 */

/* ---------------- Stage 1: 3x3 conv + bias + ReLU ----------------
 * block: 64 out-ch x (8 rows x 64 cols) pixels, 256 threads,
 * micro-tile 8m x 16px, CK=4 input channels staged in LDS.
 * launch_bounds(256,2): grid is exactly 2 blocks/CU; cap VGPR<=256 so both fit. */
__global__ __launch_bounds__(256, 2) void conv3x3_relu_k(
    const float* __restrict__ x, const float* __restrict__ W1,
    const float* __restrict__ b1, float* __restrict__ h)
{
    const int mt = blockIdx.x, yt = blockIdx.y, n = blockIdx.z;
    const int m0 = mt*64, y0 = yt*8;
    __shared__ float xs[4*680];     /* 4 ch x 10 rows x 68 cols */
    __shared__ float ws[36*64];     /* [c*9+t][m] */
    const int tid = threadIdx.x;
    const int tm = tid >> 5;        /* 0..7  -> m group */
    const int tp = tid & 31;        /* 0..31 -> pixel group */
    const int prow = tp >> 2;       /* 0..7 */
    const int pcol = (tp & 3) << 4; /* 0,16,32,48 */

    float acc[8][16];
#pragma unroll
    for (int i = 0; i < 8; ++i)
#pragma unroll
        for (int j = 0; j < 16; ++j) acc[i][j] = 0.f;

    for (int c0 = 0; c0 < CIN; c0 += 4) {
        __syncthreads();            /* previous compute must finish before restage */
        for (int i = tid; i < 4*680; i += 256) {
            int c = i / 680; int rm = i - c*680;
            int r = rm / 68; int s = rm - r*68;
            int gy = y0 + r - 1, gx = s - 1;
            float v = 0.f;
            if ((unsigned)gy < 64u && (unsigned)gx < 64u)
                v = x[(((size_t)(n*CIN + c0 + c))*64 + gy)*64 + gx];
            xs[i] = v;
        }
        for (int i = tid; i < 64*36; i += 256) {
            int m = i / 36; int j = i - m*36;
            ws[j*64 + m] = W1[(size_t)(m0+m)*4608 + c0*9 + j];
        }
        __syncthreads();
#pragma unroll 1
        for (int c = 0; c < 4; ++c) {
            const float* xb = &xs[c*680];
#pragma unroll
            for (int ky = 0; ky < 3; ++ky) {
                const float* xp = &xb[(prow+ky)*68 + pcol];
                float4 a0 = *(const float4*)(xp);
                float4 a1 = *(const float4*)(xp+4);
                float4 a2 = *(const float4*)(xp+8);
                float4 a3 = *(const float4*)(xp+12);
                float xr[18] = {a0.x,a0.y,a0.z,a0.w, a1.x,a1.y,a1.z,a1.w,
                                a2.x,a2.y,a2.z,a2.w, a3.x,a3.y,a3.z,a3.w,
                                xp[16], xp[17]};
#pragma unroll
                for (int kx = 0; kx < 3; ++kx) {
                    const float* wp = &ws[(c*9 + ky*3 + kx)*64 + tm*8];
                    float4 w0 = *(const float4*)(wp);
                    float4 w1 = *(const float4*)(wp+4);
                    float wv[8] = {w0.x,w0.y,w0.z,w0.w, w1.x,w1.y,w1.z,w1.w};
#pragma unroll
                    for (int mr = 0; mr < 8; ++mr)
#pragma unroll
                        for (int k = 0; k < 16; ++k)
                            acc[mr][k] = fmaf(wv[mr], xr[k+kx], acc[mr][k]);
                }
            }
        }
    }
#pragma unroll
    for (int mr = 0; mr < 8; ++mr) {
        int m = m0 + tm*8 + mr;
        float bias = b1[m];
        float* hp = &h[((size_t)(n*CM + m)*64 + (y0+prow))*64 + pcol];
#pragma unroll
        for (int k = 0; k < 16; ++k) {
            float v = acc[mr][k] + bias;
            hp[k] = v > 0.f ? v : 0.f;
        }
    }
}

/* ---------------- Stage 2: 1x1 heads + softmax + loc2bbox + clip + mask ---- */
__global__ __launch_bounds__(256) void rpn_head_k(
    const float* __restrict__ h, const float* __restrict__ Wsc,
    const float* __restrict__ bsc, const float* __restrict__ Wlc,
    const float* __restrict__ blc, const int* __restrict__ imh_p,
    const int* __restrict__ imw_p, float* __restrict__ out,
    float* __restrict__ roi_ws, float* __restrict__ msc_ws)
{
    const int n = blockIdx.x >> 4;
    const int pix = ((blockIdx.x & 15) << 8) + threadIdx.x;
    float accl[36], accs[18];
#pragma unroll
    for (int o = 0; o < 36; ++o) accl[o] = 0.f;
#pragma unroll
    for (int o = 0; o < 18; ++o) accs[o] = 0.f;
    const float* hp = h + (size_t)n*CM*4096 + pix;
#pragma unroll 2
    for (int c = 0; c < CIN; ++c) {
        float hv = hp[(size_t)c*4096];
#pragma unroll
        for (int o = 0; o < 36; ++o) accl[o] = fmaf(hv, Wlc[o*512 + c], accl[o]);
#pragma unroll
        for (int o = 0; o < 18; ++o) accs[o] = fmaf(hv, Wsc[o*512 + c], accs[o]);
    }
    const float imh = (float)imh_p[0];
    const float imw = (float)imw_p[0];
    const int py = pix >> 6, px = pix & 63;
    const float sx = (float)(px*16), sy = (float)(py*16);

#pragma unroll
    for (int a = 0; a < 9; ++a) {
        int ri = a/3, si = a - ri*3;
        float rr = (ri==0) ? 0.5f : (ri==1 ? 1.f : 2.f);
        float ssc = (si==0) ? 8.f : (si==1 ? 16.f : 32.f);
        float ha = 16.f*ssc*sqrtf(rr);
        float wa = 16.f*ssc*sqrtf(1.f/rr);
        float ax1 = sx - 0.5f*wa, ay1 = sy - 0.5f*ha;
        float ax2 = sx + 0.5f*wa, ay2 = sy + 0.5f*ha;
        float l0 = accl[4*a+0] + blc[4*a+0];
        float l1 = accl[4*a+1] + blc[4*a+1];
        float l2 = accl[4*a+2] + blc[4*a+2];
        float l3 = accl[4*a+3] + blc[4*a+3];
        float s0 = accs[2*a+0] + bsc[2*a+0];
        float s1 = accs[2*a+1] + bsc[2*a+1];
        float aw = ax2-ax1, ah = ay2-ay1;
        float cx = ax1 + 0.5f*aw, cy = ay1 + 0.5f*ah;
        float ncx = l0*aw + cx, ncy = l1*ah + cy;
        float nw = expf(l2)*aw, nh = expf(l3)*ah;
        float rx1 = fminf(fmaxf(ncx - 0.5f*nw, 0.f), imw);
        float ry1 = fminf(fmaxf(ncy - 0.5f*nh, 0.f), imh);
        float rx2 = fminf(fmaxf(ncx + 0.5f*nw, 0.f), imw);
        float ry2 = fminf(fmaxf(ncy + 0.5f*nh, 0.f), imh);
        float fgs = 1.f/(1.f + expf(s0 - s1));
        float sc = ((rx2-rx1) >= 16.f && (ry2-ry1) >= 16.f) ? fgs : NEGV;
        size_t ka = (size_t)pix*9 + a;
        *((float4*)(out + ((size_t)n*KA + ka)*4)) = make_float4(l0,l1,l2,l3);
        *((float2*)(out + OFF_SC + ((size_t)n*KA + ka)*2)) = make_float2(s0,s1);
        *((float4*)(roi_ws + ((size_t)n*KA + ka)*4)) = make_float4(rx1,ry1,rx2,ry2);
        msc_ws[(size_t)n*KA + ka] = sc;
        if (n == 0)
            *((float4*)(out + OFF_ANC + ka*4)) = make_float4(ax1,ay1,ax2,ay2);
    }
}

/* ---------------- Stage 3: exact top-3000 set via 3-level radix select ---- */
__device__ __forceinline__ unsigned fkey(float f) {
    unsigned u = __float_as_uint(f);
    return (u & 0x80000000u) ? ~u : (u | 0x80000000u);
}

__global__ __launch_bounds__(256) void select_topk_k(
    const float* __restrict__ msc, const float* __restrict__ roi,
    float* __restrict__ selsc, float* __restrict__ selbox)
{
    const int n = blockIdx.x, tid = threadIdx.x;
    __shared__ unsigned hist[4096];
    __shared__ unsigned aux[256];
    __shared__ unsigned sh_b, sh_gt, sh_c1, sh_c2;
    const float* sp = msc + (size_t)n*KA;
    unsigned rem = NPRE, gt_total = 0, b_acc = 0;

    for (int lv = 0; lv < 3; ++lv) {
        const int bins = (lv==2) ? 256 : 4096;
        const int shift = (lv==0) ? 20 : ((lv==1) ? 8 : 0);
        for (int i = tid; i < bins; i += 256) hist[i] = 0u;
        __syncthreads();
        for (int i = tid; i < KA; i += 256) {
            unsigned k = fkey(sp[i]);
            bool in = (lv==0) || (lv==1 ? ((k >> 20) == b_acc) : ((k >> 8) == b_acc));
            if (in) atomicAdd(&hist[(k >> shift) & (bins-1)], 1u);
        }
        __syncthreads();
        const int csz = bins >> 8;          /* 16 or 1 */
        unsigned csum = 0;
        for (int j = 0; j < csz; ++j) csum += hist[tid*csz + j];
        aux[tid] = csum;
        __syncthreads();
        for (int off = 1; off < 256; off <<= 1) {   /* inclusive suffix scan */
            unsigned v = (tid + off < 256) ? aux[tid+off] : 0u;
            __syncthreads();
            aux[tid] += v;
            __syncthreads();
        }
        unsigned r = (tid < 255) ? aux[tid+1] : 0u; /* count strictly above my chunk */
        for (int j = csz-1; j >= 0; --j) {
            int b = tid*csz + j;
            unsigned hb = hist[b];
            if (r < rem && r + hb >= rem) { sh_b = (unsigned)b; sh_gt = r; }
            r += hb;
        }
        __syncthreads();
        unsigned b = sh_b, gtab = sh_gt;
        gt_total += gtab;
        rem -= gtab;
        b_acc = (lv==0) ? b : ((b_acc << ((lv==1)?12:8)) | b);
        __syncthreads();
    }
    const unsigned T = b_acc, need_eq = rem;   /* need_eq >= 1 */
    if (tid == 0) { sh_c1 = 0u; sh_c2 = 0u; }
    __syncthreads();
    const float4* rp = (const float4*)(roi + (size_t)n*KA*4);
    float4* ob = (float4*)(selbox + (size_t)n*NPRE*4);
    float* os = selsc + (size_t)n*NPRE;
    for (int i = tid; i < KA; i += 256) {
        float s = sp[i];
        unsigned k = fkey(s);
        int p = -1;
        if (k > T) p = (int)atomicAdd(&sh_c1, 1u);
        else if (k == T) {
            unsigned e = atomicAdd(&sh_c2, 1u);
            if (e < need_eq) p = (int)(gt_total + e);
        }
        if (p >= 0) { os[p] = s; ob[p] = rp[i]; }
    }
}

/* ---------------- Stage 4: greedy NMS, 1 block/batch, scores in regs ------ */
__global__ __launch_bounds__(256) void nms_k(
    const float* __restrict__ selsc, const float* __restrict__ selbox,
    float* __restrict__ out)
{
    const int n = blockIdx.x, tid = threadIdx.x;
    __shared__ float4 box[NPRE];       /* 48 KB */
    __shared__ float red_v[4];
    __shared__ int   red_i[4];
    __shared__ float sh_v;
    __shared__ int   sh_j;
    const float4* bp = (const float4*)(selbox + (size_t)n*NPRE*4);
    for (int i = tid; i < NPRE; i += 256) box[i] = bp[i];
    float s[12], ar[12];
#pragma unroll
    for (int k = 0; k < 12; ++k) {
        int i = tid + (k<<8);
        s[k] = (i < NPRE) ? selsc[(size_t)n*NPRE + i] : -2e9f;
    }
    __syncthreads();
#pragma unroll
    for (int k = 0; k < 12; ++k) {
        int i = tid + (k<<8);
        float4 b = box[i < NPRE ? i : 0];
        ar[k] = (b.z-b.x)*(b.w-b.y);
    }
    float* rois = out + OFF_ROI + (size_t)n*NPOST*4;
    float* ridx = out + OFF_IDX + (size_t)n*NPOST;

    for (int step = 0; step < NPOST; ++step) {
        float bv = s[0]; int bi = tid;
#pragma unroll
        for (int k = 1; k < 12; ++k) {
            int i = tid + (k<<8);
            if (s[k] > bv) { bv = s[k]; bi = i; }
        }
        for (int off = 32; off > 0; off >>= 1) {
            float ov = __shfl_xor(bv, off, 64);
            int   oi = __shfl_xor(bi, off, 64);
            if (ov > bv || (ov == bv && oi < bi)) { bv = ov; bi = oi; }
        }
        int wid = tid >> 6;
        if ((tid & 63) == 0) { red_v[wid] = bv; red_i[wid] = bi; }
        __syncthreads();
        if (tid == 0) {
            float v = red_v[0]; int j = red_i[0];
#pragma unroll
            for (int w = 1; w < 4; ++w)
                if (red_v[w] > v || (red_v[w] == v && red_i[w] < j)) { v = red_v[w]; j = red_i[w]; }
            sh_v = v; sh_j = j;
        }
        __syncthreads();
        const float jv = sh_v; const int j = sh_j;
        const bool valid = jv > -5e8f;       /* NEG/2 */
        float4 jb = box[j];
        if (valid) {
            float ja = (jb.z-jb.x)*(jb.w-jb.y);
#pragma unroll
            for (int k = 0; k < 12; ++k) {
                int i = tid + (k<<8);
                if (i < NPRE && s[k] > -5e8f) {
                    float4 b = box[i];
                    float xx1 = fmaxf(b.x, jb.x), yy1 = fmaxf(b.y, jb.y);
                    float xx2 = fminf(b.z, jb.z), yy2 = fminf(b.w, jb.w);
                    float iw = fmaxf(xx2-xx1, 0.f), ih = fmaxf(yy2-yy1, 0.f);
                    float inter = iw*ih;
                    float iou = inter / (ar[k] + ja - inter + 1e-9f);
                    if (iou > 0.7f || i == j) s[k] = NEGV;
                }
            }
        }
        if (tid == 0) {
            if (valid) {
                *((float4*)(rois + step*4)) = jb;
                ridx[step] = (float)n;
            } else {
                *((float4*)(rois + step*4)) = make_float4(0.f,0.f,0.f,0.f);
                ridx[step] = -1.0f;
            }
        }
    }
}

extern "C" void kernel_launch(void* const* d_in, const int* in_sizes, int n_in,
                              void* d_out, int out_size, void* d_ws, size_t ws_size,
                              hipStream_t stream)
{
    (void)in_sizes; (void)n_in; (void)out_size; (void)ws_size;
    const float* x   = (const float*)d_in[0];
    const float* W1  = (const float*)d_in[1];
    const float* b1  = (const float*)d_in[2];
    const float* Wsc = (const float*)d_in[3];
    const float* bsc = (const float*)d_in[4];
    const float* Wlc = (const float*)d_in[5];
    const float* blc = (const float*)d_in[6];
    const int*   imh = (const int*)d_in[7];
    const int*   imw = (const int*)d_in[8];
    float* out = (float*)d_out;
    char* ws = (char*)d_ws;
    /* workspace layout (bytes, 16B aligned):
       h      : 0         .. 67108864   (8*512*64*64 f32)
       roi    : 67108864  .. 71827456   (8*36864*4 f32)
       msc    : 71827456  .. 73007104   (8*36864 f32)
       selbox : 73007104  .. 73391104   (8*3000*4 f32)
       selsc  : 73391104  .. 73487104   (8*3000 f32)   total ~70.1 MB */
    float* h      = (float*)(ws);
    float* roi    = (float*)(ws + 67108864);
    float* msc    = (float*)(ws + 71827456);
    float* selbox = (float*)(ws + 73007104);
    float* selsc  = (float*)(ws + 73391104);

    hipLaunchKernelGGL(conv3x3_relu_k, dim3(8,8,8), dim3(256), 0, stream,
                       x, W1, b1, h);
    hipLaunchKernelGGL(rpn_head_k, dim3(128), dim3(256), 0, stream,
                       h, Wsc, bsc, Wlc, blc, imh, imw, out, roi, msc);
    hipLaunchKernelGGL(select_topk_k, dim3(8), dim3(256), 0, stream,
                       msc, roi, selsc, selbox);
    hipLaunchKernelGGL(nms_k, dim3(8), dim3(256), 0, stream,
                       selsc, selbox, out);
}